// Round 1
// baseline (209.205 us; speedup 1.0000x reference)
//
#include <hip/hip_runtime.h>

#define SEQ 2048
#define DMODEL 2048
#define NHEAD 16
#define EHEAD 128
#define NE3 384   // 3*EHEAD

using short8 = __attribute__((ext_vector_type(8))) short;
using f32x4  = __attribute__((ext_vector_type(4))) float;
using f32x16 = __attribute__((ext_vector_type(16))) float;
using uint4v = __attribute__((ext_vector_type(4))) unsigned int;

__device__ __forceinline__ unsigned short f32_to_bf16(float f) {
    unsigned int u = __float_as_uint(f);
    unsigned int rounding = 0x7fffu + ((u >> 16) & 1u);
    u += rounding;
    return (unsigned short)(u >> 16);
}

// async global->LDS, 16B/lane; LDS dest = wave-uniform base + lane*16B.
__device__ __forceinline__ void async_load16(const void* g, void* l) {
    __builtin_amdgcn_global_load_lds(
        (const __attribute__((address_space(1))) unsigned int*)g,
        (__attribute__((address_space(3))) unsigned int*)l, 16, 0, 0);
}

// raw barrier: no compiler-inserted vmcnt(0) drain (that drain is the m97
// structure's ~20% stall). "" memory asms pin C-level LDS ops to their phase.
#define WG_BARRIER()                              \
    do {                                          \
        asm volatile("" ::: "memory");            \
        __builtin_amdgcn_s_barrier();             \
        asm volatile("" ::: "memory");            \
    } while (0)

// ---------------- cast x fp32 -> bf16 ----------------
__global__ void cast_x_kernel(const float* __restrict__ x, unsigned short* __restrict__ xb) {
    int i = (blockIdx.x * blockDim.x + threadIdx.x) * 4;
    float4 v = *(const float4*)(x + i);
    ushort4 o = make_ushort4(f32_to_bf16(v.x), f32_to_bf16(v.y), f32_to_bf16(v.z), f32_to_bf16(v.w));
    *(ushort4*)(xb + i) = o;
}

// ---------------- transpose + cast w: [H][D][3E] fp32 -> [H][3E][D] bf16 ----------------
__global__ void transpose_w_kernel(const float* __restrict__ w, unsigned short* __restrict__ wT) {
    __shared__ float tile[64][65];
    int h  = blockIdx.z;
    int d0 = blockIdx.x * 64;
    int n0 = blockIdx.y * 64;
    int t = threadIdx.x;
    int rr = t >> 4;           // 0..15
    int cc = (t & 15) * 4;     // 0..60
#pragma unroll
    for (int i = 0; i < 4; i++) {
        float4 v = *(const float4*)&w[(size_t)(h * DMODEL + d0 + rr + i * 16) * NE3 + n0 + cc];
        tile[rr + i * 16][cc + 0] = v.x;
        tile[rr + i * 16][cc + 1] = v.y;
        tile[rr + i * 16][cc + 2] = v.z;
        tile[rr + i * 16][cc + 3] = v.w;
    }
    __syncthreads();
#pragma unroll
    for (int i = 0; i < 4; i++) {
        int n = rr + i * 16;
        ushort4 o;
        o.x = f32_to_bf16(tile[cc + 0][n]);
        o.y = f32_to_bf16(tile[cc + 1][n]);
        o.z = f32_to_bf16(tile[cc + 2][n]);
        o.w = f32_to_bf16(tile[cc + 3][n]);
        *(ushort4*)&wT[(size_t)(h * NE3 + n0 + n) * DMODEL + d0 + cc] = o;
    }
}

// ---------------- QKV projection: 256x256 tile, BK=32, 4-deep pipelined ring ----------------
// LDS buffer b (32 KB): A subtiles [16][1024B] then B subtiles [16][1024B].
// Subtile = 16 rows x 32 k bf16, contiguous 1024 B; within a row-of-4-chunks the
// k-chunk is XORed by (row&3) — applied to BOTH the pre-swizzled global source of
// global_load_lds (LDS dest stays linear) and the ds_read address (rule #21).
// Schedule per K-tile t (buf b = t&3): 2 phases x {ds_read frags; stage half of
// tile t+3 into buf (t+3)&3 = (t-1)&3; raw barrier; setprio(1) 16 MFMA setprio(0);
// raw barrier}. Counted s_waitcnt vmcnt(8) once per K-tile (phase 1) keeps tiles
// t+2,t+3 (8 loads/thread) in flight across barriers; tail drains 8->4->0.
template <int B, bool STAGE, int VM>
__device__ __forceinline__ void qkv_kstep(
        unsigned short* lds, f32x4 (&acc)[8][4],
        const unsigned short*& sA0, const unsigned short*& sA1,
        const unsigned short*& sB0, const unsigned short*& sB1,
        const int wave, const int aoff, const int boff) {
    constexpr int B3 = (B + 3) & 3;
    const unsigned short* LA = lds + B * 16384 + aoff;
    const unsigned short* LB = lds + B * 16384 + boff;

    // ---- phase 0: A frags mf 0..3 + all B frags; stage A-half of tile t+3 ----
    short8 a0[4], bb[4];
#pragma unroll
    for (int mf = 0; mf < 4; ++mf) a0[mf] = *(const short8*)(LA + mf * 512);
#pragma unroll
    for (int nf = 0; nf < 4; ++nf) bb[nf] = *(const short8*)(LB + nf * 512);
    if constexpr (STAGE) {
        async_load16(sA0, lds + B3 * 16384 + wave * 512);
        async_load16(sA1, lds + B3 * 16384 + 4096 + wave * 512);
    }
    sA0 += 32; sA1 += 32;
    WG_BARRIER();
    __builtin_amdgcn_s_setprio(1);
#pragma unroll
    for (int mf = 0; mf < 4; ++mf)
#pragma unroll
        for (int nf = 0; nf < 4; ++nf)
            acc[mf][nf] = __builtin_amdgcn_mfma_f32_16x16x32_bf16(a0[mf], bb[nf], acc[mf][nf], 0, 0, 0);
    __builtin_amdgcn_s_setprio(0);
    WG_BARRIER();

    // ---- phase 1: A frags mf 4..7 (B reused); stage B-half; counted vmcnt ----
    short8 a1[4];
#pragma unroll
    for (int mf = 0; mf < 4; ++mf) a1[mf] = *(const short8*)(LA + (4 + mf) * 512);
    if constexpr (STAGE) {
        async_load16(sB0, lds + B3 * 16384 + 8192 + wave * 512);
        async_load16(sB1, lds + B3 * 16384 + 12288 + wave * 512);
    }
    sB0 += 32; sB1 += 32;
    if constexpr (VM == 8)      asm volatile("s_waitcnt vmcnt(8)" ::: "memory");
    else if constexpr (VM == 4) asm volatile("s_waitcnt vmcnt(4)" ::: "memory");
    else if constexpr (VM == 0) asm volatile("s_waitcnt vmcnt(0)" ::: "memory");
    WG_BARRIER();
    __builtin_amdgcn_s_setprio(1);
#pragma unroll
    for (int mf = 0; mf < 4; ++mf)
#pragma unroll
        for (int nf = 0; nf < 4; ++nf)
            acc[4 + mf][nf] = __builtin_amdgcn_mfma_f32_16x16x32_bf16(a1[mf], bb[nf], acc[4 + mf][nf], 0, 0, 0);
    __builtin_amdgcn_s_setprio(0);
    WG_BARRIER();
}

__global__ __launch_bounds__(512, 2) void qkv_gemm256(
        const unsigned short* __restrict__ A,    // xb  [2048][2048]
        const unsigned short* __restrict__ Bm,   // wT  [6144][2048]
        unsigned short* __restrict__ Q,
        unsigned short* __restrict__ Kb,
        unsigned short* __restrict__ Vt) {
    extern __shared__ __attribute__((aligned(16))) unsigned short lds[];   // 128 KB
    const int mb = blockIdx.x, nb = blockIdx.y;
    const int tid = threadIdx.x;
    const int wave = tid >> 6, lane = tid & 63;
    const int r = lane & 15, q = lane >> 4;
    const int wm = wave >> 2, wn = wave & 3;     // 2M x 4N wave grid

    // staging chunk (16B) -> (row, kcol) with the row&3 chunk-XOR pre-applied
    const int c0 = tid, c1 = tid + 512;
    const int rr0 = (c0 >> 2) & 15, rr1 = (c1 >> 2) & 15;
    const int r0 = ((c0 >> 6) << 4) + rr0, k0c = ((c0 & 3) ^ (rr0 & 3)) << 3;
    const int r1 = ((c1 >> 6) << 4) + rr1, k1c = ((c1 & 3) ^ (rr1 & 3)) << 3;

    const unsigned short* sA0 = A  + (size_t)(mb * 256 + r0) * DMODEL + k0c;
    const unsigned short* sA1 = A  + (size_t)(mb * 256 + r1) * DMODEL + k1c;
    const unsigned short* sB0 = Bm + (size_t)(nb * 256 + r0) * DMODEL + k0c;
    const unsigned short* sB1 = Bm + (size_t)(nb * 256 + r1) * DMODEL + k1c;

    // prologue: stage tiles 0..2 into bufs 0..2 (12 loads/thread)
#pragma unroll
    for (int t = 0; t < 3; ++t) {
        async_load16(sA0 + t * 32, lds + t * 16384 + wave * 512);
        async_load16(sA1 + t * 32, lds + t * 16384 + 4096 + wave * 512);
        async_load16(sB0 + t * 32, lds + t * 16384 + 8192 + wave * 512);
        async_load16(sB1 + t * 32, lds + t * 16384 + 12288 + wave * 512);
    }
    sA0 += 96; sA1 += 96; sB0 += 96; sB1 += 96;

    // per-thread fragment read offsets (shorts), chunk-XOR folded in once
    const int qs = q ^ (r & 3);
    const int aoff = wm * 4096 + r * 32 + qs * 8;
    const int boff = 8192 + wn * 2048 + r * 32 + qs * 8;

    f32x4 acc[8][4] = {};
    asm volatile("s_waitcnt vmcnt(8)" ::: "memory");   // tile 0 landed
    WG_BARRIER();

    // 64 K-tiles: 60 in the steady-state loop, 4 peeled for the drain tail
    for (int i = 0; i < 15; ++i) {
        qkv_kstep<0, true, 8>(lds, acc, sA0, sA1, sB0, sB1, wave, aoff, boff);
        qkv_kstep<1, true, 8>(lds, acc, sA0, sA1, sB0, sB1, wave, aoff, boff);
        qkv_kstep<2, true, 8>(lds, acc, sA0, sA1, sB0, sB1, wave, aoff, boff);
        qkv_kstep<3, true, 8>(lds, acc, sA0, sA1, sB0, sB1, wave, aoff, boff);
    }
    qkv_kstep<0, true,  8>(lds, acc, sA0, sA1, sB0, sB1, wave, aoff, boff);  // t=60
    qkv_kstep<1, false, 4>(lds, acc, sA0, sA1, sB0, sB1, wave, aoff, boff);  // t=61
    qkv_kstep<2, false, 0>(lds, acc, sA0, sA1, sB0, sB1, wave, aoff, boff);  // t=62
    qkv_kstep<3, false, -1>(lds, acc, sA0, sA1, sB0, sB1, wave, aoff, boff); // t=63

    // epilogue: C tile (mf,nf): row = q*4+reg, col = r (16x16x32 C layout)
    const int mbase = mb * 256 + wm * 128;
    const int nbase = nb * 256 + wn * 64;
#pragma unroll
    for (int nf = 0; nf < 4; ++nf) {
        const int cb = nbase + nf * 16;      // head/sel uniform per frag (16 | 128, 16 | 384)
        const int head = cb / 384;
        const int rem = cb - head * 384;
        const int sel = rem >> 7;
        const int e = (rem & 127) + r;
#pragma unroll
        for (int mf = 0; mf < 8; ++mf) {
            const int row0 = mbase + mf * 16 + q * 4;
            const f32x4 v = acc[mf][nf];
            if (sel == 2) {
                ushort4 o;
                o.x = f32_to_bf16(v[0]);
                o.y = f32_to_bf16(v[1]);
                o.z = f32_to_bf16(v[2]);
                o.w = f32_to_bf16(v[3]);
                *(ushort4*)&Vt[((size_t)head * EHEAD + e) * SEQ + row0] = o;
            } else {
                unsigned short* dst = sel ? Kb : Q;
#pragma unroll
                for (int reg = 0; reg < 4; ++reg)
                    dst[((size_t)head * SEQ + row0 + reg) * EHEAD + e] = f32_to_bf16(v[reg]);
            }
        }
    }
}

// ---------------- fused flash attention, 32x32 MFMA, VALU-stripped hot loop ----------------
__global__ __launch_bounds__(256, 2) void flash_attn(
        const unsigned short* __restrict__ Qg,
        const unsigned short* __restrict__ Kg,
        const unsigned short* __restrict__ Vtg,
        float* __restrict__ out) {
    extern __shared__ __attribute__((aligned(16))) unsigned short lds[];
    unsigned short* sQ  = lds;            // 8192 shorts = 16 KB   [64 m][128 k]
    unsigned short* sK0 = lds + 8192;     // 2 x 8192              [64 key][128 k]
    unsigned short* sV0 = lds + 24576;    // 2 x 8192              [128 e][64 key]

    const int tid = threadIdx.x;
    const int wave = tid >> 6, lane = tid & 63;
    const int l31 = lane & 31, q2 = lane >> 5;
    const int wm = wave >> 1, wn = wave & 1;
    const int b = blockIdx.x;
    const int h  = (b & 7) + (((b >> 3) >> 5) << 3);   // head -> XCD b%8 (K/V L2-resident)
    const int m0 = ((b >> 3) & 31) * 64;

    const unsigned short* Qh  = Qg  + ((size_t)h * SEQ + m0) * EHEAD;
    const unsigned short* Kh0 = Kg  + (size_t)h * SEQ * EHEAD;
    const unsigned short* Vh  = Vtg + (size_t)h * EHEAD * SEQ;

    const int qkRow = lane >> 4;
    const int qkPos = lane & 15;
    const int vRow  = lane >> 3;
    const int vPos  = lane & 7;

    const unsigned short* gK[4];
    const unsigned short* gV[4];
#pragma unroll
    for (int c = 0; c < 4; c++) {
        int u = wave * 4 + c;
        int row = u * 4 + qkRow;
        int ch = qkPos ^ (row & 7);
        gK[c] = Kh0 + (size_t)row * EHEAD + ch * 8;
        int rv = u * 8 + vRow;
        int cv = vPos ^ (rv & 7);
        gV[c] = Vh + (size_t)rv * SEQ + cv * 8;
        async_load16(Qh + (size_t)row * EHEAD + ch * 8, sQ + u * 512);
        async_load16(gK[c], sK0 + u * 512);
        async_load16(gV[c], sV0 + u * 512);
        gK[c] += 64 * EHEAD;
        gV[c] += 64;
    }
    __syncthreads();

    short8 bq[8];
    {
        const int row = wm * 32 + l31;
#pragma unroll
        for (int kc = 0; kc < 8; kc++) {
            int p = (kc * 2 + q2) ^ (row & 7);
            bq[kc] = *(const short8*)&sQ[row * 128 + p * 8];
        }
    }

    const unsigned short* kp[8];
    const unsigned short* vp[8];
    const int rowA = wn * 32 + l31;
#pragma unroll
    for (int kc = 0; kc < 8; kc++)
        kp[kc] = sK0 + rowA * 128 + (((kc * 2 + q2) ^ (rowA & 7)) * 8);
#pragma unroll
    for (int et = 0; et < 4; et++)
#pragma unroll
        for (int kc2 = 0; kc2 < 2; kc2++) {
            int rowV = et * 32 + l31;
            int cch = wn * 4 + kc2 * 2 + q2;
            vp[et * 2 + kc2] = sV0 + rowV * 64 + ((cch ^ (rowV & 7)) * 8);
        }

    const float c1 = 0.12752405856f;   // (1/sqrt(128)) * log2(e)
    f32x16 acc_o[4] = {};
    float l_acc = 0.f;

    auto body = [&](const int cur, const int nxt, bool pref) {
        if (pref) {
#pragma unroll
            for (int c = 0; c < 4; c++) {
                async_load16(gK[c], sK0 + nxt + (wave * 4 + c) * 512);
                gK[c] += 64 * EHEAD;
            }
#pragma unroll
            for (int c = 0; c < 4; c++) {
                async_load16(gV[c], sV0 + nxt + (wave * 4 + c) * 512);
                gV[c] += 64;
            }
        }

        f32x16 st = {};
#pragma unroll
        for (int kc = 0; kc < 8; kc++) {
            short8 ak = *(const short8*)(kp[kc] + cur);
            st = __builtin_amdgcn_mfma_f32_32x32x16_bf16(ak, bq[kc], st, 0, 0, 0);
        }

        unsigned int pk[8];
#pragma unroll
        for (int t = 0; t < 8; t++) {
            float p0 = __builtin_amdgcn_exp2f(st[2 * t] * c1);
            float p1 = __builtin_amdgcn_exp2f(st[2 * t + 1] * c1);
            l_acc += p0 + p1;
            unsigned int u0 = __float_as_uint(p0) + 0x8000u;
            unsigned int u1 = __float_as_uint(p1) + 0x8000u;
            pk[t] = __builtin_amdgcn_perm(u1, u0, 0x07060302u);
        }

        short8 fr[2];
#pragma unroll
        for (int kc2 = 0; kc2 < 2; kc2++) {
            unsigned int a0 = pk[kc2 * 4 + 0], a1 = pk[kc2 * 4 + 1];
            unsigned int a2 = pk[kc2 * 4 + 2], a3 = pk[kc2 * 4 + 3];
            unsigned int s0 = (unsigned int)__shfl_xor((int)a0, 32);
            unsigned int s1 = (unsigned int)__shfl_xor((int)a1, 32);
            unsigned int s2 = (unsigned int)__shfl_xor((int)a2, 32);
            unsigned int s3 = (unsigned int)__shfl_xor((int)a3, 32);
            uint4v t;
            t.x = q2 ? s2 : a0;
            t.y = q2 ? s3 : a1;
            t.z = q2 ? a2 : s0;
            t.w = q2 ? a3 : s1;
            fr[kc2] = __builtin_bit_cast(short8, t);
        }

#pragma unroll
        for (int et = 0; et < 4; et++)
#pragma unroll
            for (int kc2 = 0; kc2 < 2; kc2++) {
                short8 bv = *(const short8*)(vp[et * 2 + kc2] + cur);
                acc_o[et] = __builtin_amdgcn_mfma_f32_32x32x16_bf16(fr[kc2], bv, acc_o[et], 0, 0, 0);
            }
        __syncthreads();
    };

    for (int ip = 0; ip < SEQ / 128; ip++) {
        body(0, 8192, true);
        body(8192, 0, ip != SEQ / 128 - 1);
    }

    l_acc += __shfl_xor(l_acc, 32);

    float* fl = (float*)lds;
#pragma unroll
    for (int et = 0; et < 4; et++) {
        if ((et >> 1) != wn) {
#pragma unroll
            for (int rg = 0; rg < 4; rg++) {
                f32x4 v;
                v[0] = acc_o[et][rg * 4 + 0];
                v[1] = acc_o[et][rg * 4 + 1];
                v[2] = acc_o[et][rg * 4 + 2];
                v[3] = acc_o[et][rg * 4 + 3];
                *(f32x4*)&fl[(size_t)(((wm * 4 + et) * 4 + rg) * 256) + lane * 4] = v;
            }
        }
    }
    fl[8192 + (wm * 2 + wn) * 32 + l31] = l_acc;
    __syncthreads();

    float invq[4][4];
#pragma unroll
    for (int rg = 0; rg < 4; rg++)
#pragma unroll
        for (int i = 0; i < 4; i++) {
            int qy = i + 4 * q2 + 8 * rg;
            float lt = fl[8192 + (wm * 2 + 0) * 32 + qy] + fl[8192 + (wm * 2 + 1) * 32 + qy];
            invq[rg][i] = 1.0f / lt;
        }

#pragma unroll
    for (int et = 0; et < 4; et++) {
        if ((et >> 1) == wn) {
#pragma unroll
            for (int rg = 0; rg < 4; rg++) {
                f32x4 v = *(const f32x4*)&fl[(size_t)(((wm * 4 + et) * 4 + rg) * 256) + lane * 4];
#pragma unroll
                for (int i = 0; i < 4; i++) {
                    int mrow = i + 4 * q2 + 8 * rg;
                    out[(size_t)(m0 + wm * 32 + mrow) * DMODEL + h * EHEAD + et * 32 + l31] =
                        (acc_o[et][rg * 4 + i] + v[i]) * invq[rg][i];
                }
            }
        }
    }
}

extern "C" void kernel_launch(void* const* d_in, const int* in_sizes, int n_in,
                              void* d_out, int out_size, void* d_ws, size_t ws_size,
                              hipStream_t stream) {
    const float* x = (const float*)d_in[0];      // [S][D]
    const float* w = (const float*)d_in[1];      // [H][D][3E]
    float* out = (float*)d_out;                  // [S][H*E]

    char* ws = (char*)d_ws;
    unsigned short* xb = (unsigned short*)(ws);                        //  8 MB
    unsigned short* wT = (unsigned short*)(ws + 8388608);              // 24 MB
    unsigned short* Q  = (unsigned short*)(ws + 33554432);             //  8 MB
    unsigned short* Kb = (unsigned short*)(ws + 41943040);             //  8 MB
    unsigned short* Vt = (unsigned short*)(ws + 50331648);             //  8 MB

    static bool attr_set = false;
    if (!attr_set) {
        hipFuncSetAttribute((const void*)flash_attn,
                            hipFuncAttributeMaxDynamicSharedMemorySize, 81920);
        hipFuncSetAttribute((const void*)qkv_gemm256,
                            hipFuncAttributeMaxDynamicSharedMemorySize, 131072);
        attr_set = true;
    }

    cast_x_kernel<<<SEQ * DMODEL / (256 * 4), 256, 0, stream>>>(x, xb);
    transpose_w_kernel<<<dim3(DMODEL / 64, NE3 / 64, NHEAD), 256, 0, stream>>>(w, wT);
    qkv_gemm256<<<dim3(SEQ / 256, (NHEAD * NE3) / 256), 512, 131072, stream>>>(xb, wT, Q, Kb, Vt);
    flash_attn<<<512, 256, 81920, stream>>>(Q, Kb, Vt, out);
}

// Round 2
// 202.796 us; speedup vs baseline: 1.0316x; 1.0316x over previous
//
#include <hip/hip_runtime.h>

#define SEQ 2048
#define DMODEL 2048
#define NHEAD 16
#define EHEAD 128
#define NE3 384   // 3*EHEAD

using short8 = __attribute__((ext_vector_type(8))) short;
using f32x4  = __attribute__((ext_vector_type(4))) float;
using f32x16 = __attribute__((ext_vector_type(16))) float;
using uint4v = __attribute__((ext_vector_type(4))) unsigned int;

__device__ __forceinline__ unsigned short f32_to_bf16(float f) {
    unsigned int u = __float_as_uint(f);
    unsigned int rounding = 0x7fffu + ((u >> 16) & 1u);
    u += rounding;
    return (unsigned short)(u >> 16);
}

// async global->LDS, 16B/lane; LDS dest = wave-uniform base + lane*16B.
__device__ __forceinline__ void async_load16(const void* g, void* l) {
    __builtin_amdgcn_global_load_lds(
        (const __attribute__((address_space(1))) unsigned int*)g,
        (__attribute__((address_space(3))) unsigned int*)l, 16, 0, 0);
}

// raw barrier: no compiler-inserted vmcnt(0) drain.
#define WG_BARRIER()                              \
    do {                                          \
        asm volatile("" ::: "memory");            \
        __builtin_amdgcn_s_barrier();             \
        asm volatile("" ::: "memory");            \
    } while (0)

// ---------------- cast x fp32 -> bf16 ----------------
__global__ void cast_x_kernel(const float* __restrict__ x, unsigned short* __restrict__ xb) {
    int i = (blockIdx.x * blockDim.x + threadIdx.x) * 4;
    float4 v = *(const float4*)(x + i);
    ushort4 o = make_ushort4(f32_to_bf16(v.x), f32_to_bf16(v.y), f32_to_bf16(v.z), f32_to_bf16(v.w));
    *(ushort4*)(xb + i) = o;
}

// ---------------- transpose + cast w: [H][D][3E] fp32 -> [H][3E][D] bf16 ----------------
__global__ void transpose_w_kernel(const float* __restrict__ w, unsigned short* __restrict__ wT) {
    __shared__ float tile[64][65];
    int h  = blockIdx.z;
    int d0 = blockIdx.x * 64;
    int n0 = blockIdx.y * 64;
    int t = threadIdx.x;
    int rr = t >> 4;           // 0..15
    int cc = (t & 15) * 4;     // 0..60
#pragma unroll
    for (int i = 0; i < 4; i++) {
        float4 v = *(const float4*)&w[(size_t)(h * DMODEL + d0 + rr + i * 16) * NE3 + n0 + cc];
        tile[rr + i * 16][cc + 0] = v.x;
        tile[rr + i * 16][cc + 1] = v.y;
        tile[rr + i * 16][cc + 2] = v.z;
        tile[rr + i * 16][cc + 3] = v.w;
    }
    __syncthreads();
#pragma unroll
    for (int i = 0; i < 4; i++) {
        int n = rr + i * 16;
        ushort4 o;
        o.x = f32_to_bf16(tile[cc + 0][n]);
        o.y = f32_to_bf16(tile[cc + 1][n]);
        o.z = f32_to_bf16(tile[cc + 2][n]);
        o.w = f32_to_bf16(tile[cc + 3][n]);
        *(ushort4*)&wT[(size_t)(h * NE3 + n0 + n) * DMODEL + d0 + cc] = o;
    }
}

// ---------------- QKV projection: 128x384 tile (one head per block), BK=32 ----------------
// Grid 16x16 = 256 blocks = exactly 1/CU (128 KB LDS ring). LDS buffer (32 KB):
// A [128 rows][32 k] then B [384 rows][32 k], as [16-row][32-k] subtiles of 1024 B.
// Swizzle: within a row, 16B k-chunk slot = kc ^ ((row>>1)&3) — applied to the
// pre-swizzled GLOBAL source of global_load_lds (LDS dest linear) and to the
// ds_read address (both-sides involution). Fragment read slot within the 128 B
// bank period = 4*(r&1) + (q ^ ((r>>1)&3)): each 16-lane quarter hits all 8
// slots exactly 2x -> 2-way (free). [Round-1's (r&3) key gave 4-way.]
// Schedule per K-tile t (buf t&3): 2 phases x {ds_read frags; stage 2 chunks of
// tile t+3; barrier; setprio(1) 12 MFMA setprio(0); barrier}. Counted vmcnt(8)
// once per K-tile keeps tiles t+2,t+3 (8 loads/thread) in flight; tail 8->4->0.
template <int B, bool STAGE, int VM>
__device__ __forceinline__ void qkv_kstep(
        unsigned short* lds, f32x4 (&acc)[4][6],
        const unsigned short*& p0, const unsigned short*& p1,
        const unsigned short*& p2, const unsigned short*& p3,
        const int d0, const int d1, const int d2, const int d3,
        const int aoff, const int boff) {
    constexpr int B3 = ((B + 3) & 3) * 16384;
    const unsigned short* LA = lds + B * 16384 + aoff;
    const unsigned short* LB = lds + B * 16384 + boff;

    // ---- phase 0: A frags + B frags nf 0..2; stage A + B-third of tile t+3 ----
    short8 a[4], b0[3];
#pragma unroll
    for (int mf = 0; mf < 4; ++mf) a[mf] = *(const short8*)(LA + mf * 512);
#pragma unroll
    for (int nf = 0; nf < 3; ++nf) b0[nf] = *(const short8*)(LB + nf * 512);
    if constexpr (STAGE) {
        async_load16(p0, lds + B3 + d0);
        async_load16(p1, lds + B3 + d1);
    }
    p0 += 32; p1 += 32;
    WG_BARRIER();
    __builtin_amdgcn_s_setprio(1);
#pragma unroll
    for (int mf = 0; mf < 4; ++mf)
#pragma unroll
        for (int nf = 0; nf < 3; ++nf)
            acc[mf][nf] = __builtin_amdgcn_mfma_f32_16x16x32_bf16(a[mf], b0[nf], acc[mf][nf], 0, 0, 0);
    __builtin_amdgcn_s_setprio(0);
    WG_BARRIER();

    // ---- phase 1: B frags nf 3..5 (A reused); stage rest; counted vmcnt ----
    short8 b1[3];
#pragma unroll
    for (int nf = 0; nf < 3; ++nf) b1[nf] = *(const short8*)(LB + (3 + nf) * 512);
    if constexpr (STAGE) {
        async_load16(p2, lds + B3 + d2);
        async_load16(p3, lds + B3 + d3);
    }
    p2 += 32; p3 += 32;
    if constexpr (VM == 8)      asm volatile("s_waitcnt vmcnt(8)" ::: "memory");
    else if constexpr (VM == 4) asm volatile("s_waitcnt vmcnt(4)" ::: "memory");
    else if constexpr (VM == 0) asm volatile("s_waitcnt vmcnt(0)" ::: "memory");
    WG_BARRIER();
    __builtin_amdgcn_s_setprio(1);
#pragma unroll
    for (int mf = 0; mf < 4; ++mf)
#pragma unroll
        for (int nf = 0; nf < 3; ++nf)
            acc[mf][3 + nf] = __builtin_amdgcn_mfma_f32_16x16x32_bf16(a[mf], b1[nf], acc[mf][3 + nf], 0, 0, 0);
    __builtin_amdgcn_s_setprio(0);
    WG_BARRIER();
}

__global__ __launch_bounds__(512, 2) void qkv_gemm384(
        const unsigned short* __restrict__ A,    // xb  [2048][2048]
        const unsigned short* __restrict__ Bm,   // wT  [6144][2048]
        unsigned short* __restrict__ Q,
        unsigned short* __restrict__ Kb,
        unsigned short* __restrict__ Vt) {
    extern __shared__ __attribute__((aligned(16))) unsigned short lds[];   // 128 KB
    const int mb = blockIdx.x, nb = blockIdx.y;   // nb == head
    const int tid = threadIdx.x;
    const int wave = tid >> 6, lane = tid & 63;
    const int r = lane & 15, q = lane >> 4;
    const int wm = wave >> 2, wn = wave & 3;      // 2M x 4N wave grid, per-wave 64x96

    // staging: 2048 chunks/tile (A 512 + B 1536), 4 chunks/thread, all uniform.
    // chunk c: subtile c>>6, row-in-subtile (c>>2)&15, k-chunk c&3.
    const int rrm  = (tid >> 2) & 15;
    const int kg   = ((tid & 3) ^ ((rrm >> 1) & 3)) * 8;   // pre-swizzled global k
    const int rowA = ((tid >> 6) << 4) + rrm;              // 0..127
    const unsigned short* p0 = A  + (size_t)(mb * 128 + rowA) * DMODEL + kg;
    const unsigned short* p1 = Bm + (size_t)(nb * 384 + rowA) * DMODEL + kg;
    const unsigned short* p2 = p1 + (size_t)128 * DMODEL;
    const unsigned short* p3 = p1 + (size_t)256 * DMODEL;
    const int d0 = wave * 512;                 // LDS dests (shorts, wave-uniform)
    const int d1 = 4096 + wave * 512;
    const int d2 = 8192 + wave * 512;
    const int d3 = 12288 + wave * 512;

    // prologue: stage tiles 0..2 into bufs 0..2
#pragma unroll
    for (int t = 0; t < 3; ++t) {
        async_load16(p0 + t * 32, lds + t * 16384 + d0);
        async_load16(p1 + t * 32, lds + t * 16384 + d1);
        async_load16(p2 + t * 32, lds + t * 16384 + d2);
        async_load16(p3 + t * 32, lds + t * 16384 + d3);
    }
    p0 += 96; p1 += 96; p2 += 96; p3 += 96;

    // fragment read offsets (shorts): slot XOR key is (r>>1)&3
    const int qs = q ^ ((r >> 1) & 3);
    const int aoff = wm * 2048 + r * 32 + qs * 8;
    const int boff = 4096 + wn * 3072 + r * 32 + qs * 8;

    f32x4 acc[4][6] = {};
    asm volatile("s_waitcnt vmcnt(8)" ::: "memory");   // tile 0 landed
    WG_BARRIER();

    for (int i = 0; i < 15; ++i) {
        qkv_kstep<0, true, 8>(lds, acc, p0, p1, p2, p3, d0, d1, d2, d3, aoff, boff);
        qkv_kstep<1, true, 8>(lds, acc, p0, p1, p2, p3, d0, d1, d2, d3, aoff, boff);
        qkv_kstep<2, true, 8>(lds, acc, p0, p1, p2, p3, d0, d1, d2, d3, aoff, boff);
        qkv_kstep<3, true, 8>(lds, acc, p0, p1, p2, p3, d0, d1, d2, d3, aoff, boff);
    }
    qkv_kstep<0, true,  8>(lds, acc, p0, p1, p2, p3, d0, d1, d2, d3, aoff, boff);  // t=60
    qkv_kstep<1, false, 4>(lds, acc, p0, p1, p2, p3, d0, d1, d2, d3, aoff, boff);  // t=61
    qkv_kstep<2, false, 0>(lds, acc, p0, p1, p2, p3, d0, d1, d2, d3, aoff, boff);  // t=62
    qkv_kstep<3, false, -1>(lds, acc, p0, p1, p2, p3, d0, d1, d2, d3, aoff, boff); // t=63

    // epilogue: C frag (mf,nf): row = q*4+reg, col = r. One head per block.
    const int head = nb;
    const int mbase = mb * 128 + wm * 64;
#pragma unroll
    for (int nf = 0; nf < 6; ++nf) {
        const int cb = wn * 96 + nf * 16;        // 0..368, multiple of 16
        const int sel = cb >> 7;                 // 0=Q 1=K 2=V (wave-uniform)
        const int e = (cb & 127) + r;
#pragma unroll
        for (int mf = 0; mf < 4; ++mf) {
            const int row0 = mbase + mf * 16 + q * 4;
            const f32x4 v = acc[mf][nf];
            if (sel == 2) {
                ushort4 o;
                o.x = f32_to_bf16(v[0]);
                o.y = f32_to_bf16(v[1]);
                o.z = f32_to_bf16(v[2]);
                o.w = f32_to_bf16(v[3]);
                *(ushort4*)&Vt[((size_t)head * EHEAD + e) * SEQ + row0] = o;
            } else {
                unsigned short* dst = sel ? Kb : Q;
#pragma unroll
                for (int reg = 0; reg < 4; ++reg)
                    dst[((size_t)head * SEQ + row0 + reg) * EHEAD + e] = f32_to_bf16(v[reg]);
            }
        }
    }
}

// ---------------- fused flash attention, 32x32 MFMA, VALU-stripped hot loop ----------------
__global__ __launch_bounds__(256, 2) void flash_attn(
        const unsigned short* __restrict__ Qg,
        const unsigned short* __restrict__ Kg,
        const unsigned short* __restrict__ Vtg,
        float* __restrict__ out) {
    extern __shared__ __attribute__((aligned(16))) unsigned short lds[];
    unsigned short* sQ  = lds;            // 8192 shorts = 16 KB   [64 m][128 k]
    unsigned short* sK0 = lds + 8192;     // 2 x 8192              [64 key][128 k]
    unsigned short* sV0 = lds + 24576;    // 2 x 8192              [128 e][64 key]

    const int tid = threadIdx.x;
    const int wave = tid >> 6, lane = tid & 63;
    const int l31 = lane & 31, q2 = lane >> 5;
    const int wm = wave >> 1, wn = wave & 1;
    const int b = blockIdx.x;
    const int h  = (b & 7) + (((b >> 3) >> 5) << 3);   // head -> XCD b%8 (K/V L2-resident)
    const int m0 = ((b >> 3) & 31) * 64;

    const unsigned short* Qh  = Qg  + ((size_t)h * SEQ + m0) * EHEAD;
    const unsigned short* Kh0 = Kg  + (size_t)h * SEQ * EHEAD;
    const unsigned short* Vh  = Vtg + (size_t)h * EHEAD * SEQ;

    const int qkRow = lane >> 4;
    const int qkPos = lane & 15;
    const int vRow  = lane >> 3;
    const int vPos  = lane & 7;

    const unsigned short* gK[4];
    const unsigned short* gV[4];
#pragma unroll
    for (int c = 0; c < 4; c++) {
        int u = wave * 4 + c;
        int row = u * 4 + qkRow;
        int ch = qkPos ^ (row & 7);
        gK[c] = Kh0 + (size_t)row * EHEAD + ch * 8;
        int rv = u * 8 + vRow;
        int cv = vPos ^ (rv & 7);
        gV[c] = Vh + (size_t)rv * SEQ + cv * 8;
        async_load16(Qh + (size_t)row * EHEAD + ch * 8, sQ + u * 512);
        async_load16(gK[c], sK0 + u * 512);
        async_load16(gV[c], sV0 + u * 512);
        gK[c] += 64 * EHEAD;
        gV[c] += 64;
    }
    __syncthreads();

    short8 bq[8];
    {
        const int row = wm * 32 + l31;
#pragma unroll
        for (int kc = 0; kc < 8; kc++) {
            int p = (kc * 2 + q2) ^ (row & 7);
            bq[kc] = *(const short8*)&sQ[row * 128 + p * 8];
        }
    }

    const unsigned short* kp[8];
    const unsigned short* vp[8];
    const int rowA = wn * 32 + l31;
#pragma unroll
    for (int kc = 0; kc < 8; kc++)
        kp[kc] = sK0 + rowA * 128 + (((kc * 2 + q2) ^ (rowA & 7)) * 8);
#pragma unroll
    for (int et = 0; et < 4; et++)
#pragma unroll
        for (int kc2 = 0; kc2 < 2; kc2++) {
            int rowV = et * 32 + l31;
            int cch = wn * 4 + kc2 * 2 + q2;
            vp[et * 2 + kc2] = sV0 + rowV * 64 + ((cch ^ (rowV & 7)) * 8);
        }

    const float c1 = 0.12752405856f;   // (1/sqrt(128)) * log2(e)
    f32x16 acc_o[4] = {};
    float l_acc = 0.f;

    auto body = [&](const int cur, const int nxt, bool pref) {
        if (pref) {
#pragma unroll
            for (int c = 0; c < 4; c++) {
                async_load16(gK[c], sK0 + nxt + (wave * 4 + c) * 512);
                gK[c] += 64 * EHEAD;
            }
#pragma unroll
            for (int c = 0; c < 4; c++) {
                async_load16(gV[c], sV0 + nxt + (wave * 4 + c) * 512);
                gV[c] += 64;
            }
        }

        f32x16 st = {};
#pragma unroll
        for (int kc = 0; kc < 8; kc++) {
            short8 ak = *(const short8*)(kp[kc] + cur);
            st = __builtin_amdgcn_mfma_f32_32x32x16_bf16(ak, bq[kc], st, 0, 0, 0);
        }

        unsigned int pk[8];
#pragma unroll
        for (int t = 0; t < 8; t++) {
            float p0 = __builtin_amdgcn_exp2f(st[2 * t] * c1);
            float p1 = __builtin_amdgcn_exp2f(st[2 * t + 1] * c1);
            l_acc += p0 + p1;
            unsigned int u0 = __float_as_uint(p0) + 0x8000u;
            unsigned int u1 = __float_as_uint(p1) + 0x8000u;
            pk[t] = __builtin_amdgcn_perm(u1, u0, 0x07060302u);
        }

        short8 fr[2];
#pragma unroll
        for (int kc2 = 0; kc2 < 2; kc2++) {
            unsigned int a0 = pk[kc2 * 4 + 0], a1 = pk[kc2 * 4 + 1];
            unsigned int a2 = pk[kc2 * 4 + 2], a3 = pk[kc2 * 4 + 3];
            unsigned int s0 = (unsigned int)__shfl_xor((int)a0, 32);
            unsigned int s1 = (unsigned int)__shfl_xor((int)a1, 32);
            unsigned int s2 = (unsigned int)__shfl_xor((int)a2, 32);
            unsigned int s3 = (unsigned int)__shfl_xor((int)a3, 32);
            uint4v t;
            t.x = q2 ? s2 : a0;
            t.y = q2 ? s3 : a1;
            t.z = q2 ? a2 : s0;
            t.w = q2 ? a3 : s1;
            fr[kc2] = __builtin_bit_cast(short8, t);
        }

#pragma unroll
        for (int et = 0; et < 4; et++)
#pragma unroll
            for (int kc2 = 0; kc2 < 2; kc2++) {
                short8 bv = *(const short8*)(vp[et * 2 + kc2] + cur);
                acc_o[et] = __builtin_amdgcn_mfma_f32_32x32x16_bf16(fr[kc2], bv, acc_o[et], 0, 0, 0);
            }
        __syncthreads();
    };

    for (int ip = 0; ip < SEQ / 128; ip++) {
        body(0, 8192, true);
        body(8192, 0, ip != SEQ / 128 - 1);
    }

    l_acc += __shfl_xor(l_acc, 32);

    float* fl = (float*)lds;
#pragma unroll
    for (int et = 0; et < 4; et++) {
        if ((et >> 1) != wn) {
#pragma unroll
            for (int rg = 0; rg < 4; rg++) {
                f32x4 v;
                v[0] = acc_o[et][rg * 4 + 0];
                v[1] = acc_o[et][rg * 4 + 1];
                v[2] = acc_o[et][rg * 4 + 2];
                v[3] = acc_o[et][rg * 4 + 3];
                *(f32x4*)&fl[(size_t)(((wm * 4 + et) * 4 + rg) * 256) + lane * 4] = v;
            }
        }
    }
    fl[8192 + (wm * 2 + wn) * 32 + l31] = l_acc;
    __syncthreads();

    float invq[4][4];
#pragma unroll
    for (int rg = 0; rg < 4; rg++)
#pragma unroll
        for (int i = 0; i < 4; i++) {
            int qy = i + 4 * q2 + 8 * rg;
            float lt = fl[8192 + (wm * 2 + 0) * 32 + qy] + fl[8192 + (wm * 2 + 1) * 32 + qy];
            invq[rg][i] = 1.0f / lt;
        }

#pragma unroll
    for (int et = 0; et < 4; et++) {
        if ((et >> 1) == wn) {
#pragma unroll
            for (int rg = 0; rg < 4; rg++) {
                f32x4 v = *(const f32x4*)&fl[(size_t)(((wm * 4 + et) * 4 + rg) * 256) + lane * 4];
#pragma unroll
                for (int i = 0; i < 4; i++) {
                    int mrow = i + 4 * q2 + 8 * rg;
                    out[(size_t)(m0 + wm * 32 + mrow) * DMODEL + h * EHEAD + et * 32 + l31] =
                        (acc_o[et][rg * 4 + i] + v[i]) * invq[rg][i];
                }
            }
        }
    }
}

extern "C" void kernel_launch(void* const* d_in, const int* in_sizes, int n_in,
                              void* d_out, int out_size, void* d_ws, size_t ws_size,
                              hipStream_t stream) {
    const float* x = (const float*)d_in[0];      // [S][D]
    const float* w = (const float*)d_in[1];      // [H][D][3E]
    float* out = (float*)d_out;                  // [S][H*E]

    char* ws = (char*)d_ws;
    unsigned short* xb = (unsigned short*)(ws);                        //  8 MB
    unsigned short* wT = (unsigned short*)(ws + 8388608);              // 24 MB
    unsigned short* Q  = (unsigned short*)(ws + 33554432);             //  8 MB
    unsigned short* Kb = (unsigned short*)(ws + 41943040);             //  8 MB
    unsigned short* Vt = (unsigned short*)(ws + 50331648);             //  8 MB

    static bool attr_set = false;
    if (!attr_set) {
        hipFuncSetAttribute((const void*)flash_attn,
                            hipFuncAttributeMaxDynamicSharedMemorySize, 81920);
        hipFuncSetAttribute((const void*)qkv_gemm384,
                            hipFuncAttributeMaxDynamicSharedMemorySize, 131072);
        attr_set = true;
    }

    cast_x_kernel<<<SEQ * DMODEL / (256 * 4), 256, 0, stream>>>(x, xb);
    transpose_w_kernel<<<dim3(DMODEL / 64, NE3 / 64, NHEAD), 256, 0, stream>>>(w, wT);
    qkv_gemm384<<<dim3(SEQ / 128, NHEAD), 512, 131072, stream>>>(xb, wT, Q, Kb, Vt);
    flash_attn<<<512, 256, 81920, stream>>>(Q, Kb, Vt, out);
}

// Round 3
// 196.638 us; speedup vs baseline: 1.0639x; 1.0313x over previous
//
#include <hip/hip_runtime.h>

#define SEQ 2048
#define DMODEL 2048
#define NHEAD 16
#define EHEAD 128
#define NE3 384   // 3*EHEAD

using short8 = __attribute__((ext_vector_type(8))) short;
using f32x4  = __attribute__((ext_vector_type(4))) float;
using f32x16 = __attribute__((ext_vector_type(16))) float;
using uint4v = __attribute__((ext_vector_type(4))) unsigned int;

__device__ __forceinline__ unsigned short f32_to_bf16(float f) {
    unsigned int u = __float_as_uint(f);
    unsigned int rounding = 0x7fffu + ((u >> 16) & 1u);
    u += rounding;
    return (unsigned short)(u >> 16);
}

// async global->LDS, 16B/lane; LDS dest = wave-uniform base + lane*16B.
__device__ __forceinline__ void async_load16(const void* g, void* l) {
    __builtin_amdgcn_global_load_lds(
        (const __attribute__((address_space(1))) unsigned int*)g,
        (__attribute__((address_space(3))) unsigned int*)l, 16, 0, 0);
}

// ---------------- cast x fp32 -> bf16 ----------------
__global__ void cast_x_kernel(const float* __restrict__ x, unsigned short* __restrict__ xb) {
    int i = (blockIdx.x * blockDim.x + threadIdx.x) * 4;
    float4 v = *(const float4*)(x + i);
    ushort4 o = make_ushort4(f32_to_bf16(v.x), f32_to_bf16(v.y), f32_to_bf16(v.z), f32_to_bf16(v.w));
    *(ushort4*)(xb + i) = o;
}

// ---------------- transpose + cast w: [H][D][3E] fp32 -> [H][3E][D] bf16 ----------------
__global__ void transpose_w_kernel(const float* __restrict__ w, unsigned short* __restrict__ wT) {
    __shared__ float tile[64][65];
    int h  = blockIdx.z;
    int d0 = blockIdx.x * 64;
    int n0 = blockIdx.y * 64;
    int t = threadIdx.x;
    int rr = t >> 4;           // 0..15
    int cc = (t & 15) * 4;     // 0..60
#pragma unroll
    for (int i = 0; i < 4; i++) {
        float4 v = *(const float4*)&w[(size_t)(h * DMODEL + d0 + rr + i * 16) * NE3 + n0 + cc];
        tile[rr + i * 16][cc + 0] = v.x;
        tile[rr + i * 16][cc + 1] = v.y;
        tile[rr + i * 16][cc + 2] = v.z;
        tile[rr + i * 16][cc + 3] = v.w;
    }
    __syncthreads();
#pragma unroll
    for (int i = 0; i < 4; i++) {
        int n = rr + i * 16;
        ushort4 o;
        o.x = f32_to_bf16(tile[cc + 0][n]);
        o.y = f32_to_bf16(tile[cc + 1][n]);
        o.z = f32_to_bf16(tile[cc + 2][n]);
        o.w = f32_to_bf16(tile[cc + 3][n]);
        *(ushort4*)&wT[(size_t)(h * NE3 + n0 + n) * DMODEL + d0 + cc] = o;
    }
}

// ---------------- QKV projection: 128x384 tile (one head per block), BK=32 ----------------
// Grid 16x16 = 256 blocks = 1/CU. Ring-4 LDS (4 x 32 KB): buffer = A [128][32] then
// B [384][32] as 16-row x 32-k subtiles (1024 B each); 16B-chunk slot within a row
// is XORed by ((row>>1)&3), applied BOTH to the pre-swizzled global source of
// global_load_lds (LDS dest linear) and to the ds_read address (involution, 0 bank
// conflicts measured r2). Schedule per K-tile t (buf t&3, bare s_barrier ONLY —
// memory-clobber asm around barriers forces vmcnt(0) drains and was r1/r2's bug):
//   PH0: ds_read b1 (this tile nf3..5); stage 2 chunks of tile t+3; vmcnt(6) gate
//        (buf t+1 landed; 6 = 4 loads of t-1 + 2 just issued); barrier;
//        setprio(1) 12 MFMA (a x b0) setprio(0); barrier.
//   PH1: ds_read NEXT tile's a[4],b0[3] from buf t+1 (one phase ahead -> compiler
//        emits counted lgkmcnt(3)/(7), not drains); stage 2 chunks; barrier;
//        setprio(1) 12 MFMA (a x b1) setprio(0); barrier.
// Tail gates 6 -> 4 -> 0; tiles 61..63 don't stage.
template <int B, bool STAGE, int VM, bool RDNEXT>
__device__ __forceinline__ void qkv_kstep(
        unsigned short* lds, f32x4 (&acc)[4][6],
        short8 (&aC)[4], short8 (&bC)[3],     // this tile's ph0 frags (read last tile)
        short8 (&aN)[4], short8 (&bN)[3],     // next tile's ph0 frags (read here)
        const unsigned short*& p0, const unsigned short*& p1,
        const unsigned short*& p2, const unsigned short*& p3,
        const int d0, const int d1, const int d2, const int d3,
        const int aoff, const int boff) {
    constexpr int CUR = B * 16384;
    constexpr int NXT = ((B + 1) & 3) * 16384;
    constexpr int DST = ((B + 3) & 3) * 16384;

    // ---- phase 0 ----
    short8 b1[3];
#pragma unroll
    for (int nf = 0; nf < 3; ++nf) b1[nf] = *(const short8*)(lds + CUR + boff + (3 + nf) * 512);
    if constexpr (STAGE) {
        async_load16(p0, lds + DST + d0);
        async_load16(p1, lds + DST + d1);
    }
    p0 += 32; p1 += 32;
    if constexpr (VM == 6)      asm volatile("s_waitcnt vmcnt(6)");
    else if constexpr (VM == 4) asm volatile("s_waitcnt vmcnt(4)");
    else if constexpr (VM == 0) asm volatile("s_waitcnt vmcnt(0)");
    __builtin_amdgcn_s_barrier();
    __builtin_amdgcn_s_setprio(1);
#pragma unroll
    for (int mf = 0; mf < 4; ++mf)
#pragma unroll
        for (int nf = 0; nf < 3; ++nf)
            acc[mf][nf] = __builtin_amdgcn_mfma_f32_16x16x32_bf16(aC[mf], bC[nf], acc[mf][nf], 0, 0, 0);
    __builtin_amdgcn_s_setprio(0);
    __builtin_amdgcn_s_barrier();

    // ---- phase 1 ----
    if constexpr (RDNEXT) {
#pragma unroll
        for (int mf = 0; mf < 4; ++mf) aN[mf] = *(const short8*)(lds + NXT + aoff + mf * 512);
#pragma unroll
        for (int nf = 0; nf < 3; ++nf) bN[nf] = *(const short8*)(lds + NXT + boff + nf * 512);
    }
    if constexpr (STAGE) {
        async_load16(p2, lds + DST + d2);
        async_load16(p3, lds + DST + d3);
    }
    p2 += 32; p3 += 32;
    __builtin_amdgcn_s_barrier();
    __builtin_amdgcn_s_setprio(1);
#pragma unroll
    for (int mf = 0; mf < 4; ++mf)
#pragma unroll
        for (int nf = 0; nf < 3; ++nf)
            acc[mf][3 + nf] = __builtin_amdgcn_mfma_f32_16x16x32_bf16(aC[mf], b1[nf], acc[mf][3 + nf], 0, 0, 0);
    __builtin_amdgcn_s_setprio(0);
    __builtin_amdgcn_s_barrier();
}

__global__ __launch_bounds__(512, 2) void qkv_gemm384(
        const unsigned short* __restrict__ A,    // xb  [2048][2048]
        const unsigned short* __restrict__ Bm,   // wT  [6144][2048]
        unsigned short* __restrict__ Q,
        unsigned short* __restrict__ Kb,
        unsigned short* __restrict__ Vt) {
    extern __shared__ __attribute__((aligned(16))) unsigned short lds[];   // 128 KB
    const int mb = blockIdx.x, nb = blockIdx.y;   // nb == head
    const int tid = threadIdx.x;
    const int wave = tid >> 6, lane = tid & 63;
    const int r = lane & 15, q = lane >> 4;
    const int wm = wave >> 2, wn = wave & 3;      // 2M x 4N wave grid, per-wave 64x96

    // staging: 2048 chunks/tile (A 512 + B 1536), 4 chunks/thread, all uniform.
    const int rrm  = (tid >> 2) & 15;
    const int kg   = ((tid & 3) ^ ((rrm >> 1) & 3)) * 8;   // pre-swizzled global k
    const int rowA = ((tid >> 6) << 4) + rrm;              // 0..127
    const unsigned short* p0 = A  + (size_t)(mb * 128 + rowA) * DMODEL + kg;
    const unsigned short* p1 = Bm + (size_t)(nb * 384 + rowA) * DMODEL + kg;
    const unsigned short* p2 = p1 + (size_t)128 * DMODEL;
    const unsigned short* p3 = p1 + (size_t)256 * DMODEL;
    const int d0 = wave * 512;                 // LDS dests (shorts, wave-uniform)
    const int d1 = 4096 + wave * 512;
    const int d2 = 8192 + wave * 512;
    const int d3 = 12288 + wave * 512;

    // prologue: stage tiles 0..2 into bufs 0..2
#pragma unroll
    for (int t = 0; t < 3; ++t) {
        async_load16(p0 + t * 32, lds + t * 16384 + d0);
        async_load16(p1 + t * 32, lds + t * 16384 + d1);
        async_load16(p2 + t * 32, lds + t * 16384 + d2);
        async_load16(p3 + t * 32, lds + t * 16384 + d3);
    }
    p0 += 96; p1 += 96; p2 += 96; p3 += 96;

    // fragment read offsets (shorts): slot XOR key is (r>>1)&3
    const int qs = q ^ ((r >> 1) & 3);
    const int aoff = wm * 2048 + r * 32 + qs * 8;
    const int boff = 4096 + wn * 3072 + r * 32 + qs * 8;

    f32x4 acc[4][6] = {};
    asm volatile("s_waitcnt vmcnt(8)");   // own tile-0 loads landed
    __builtin_amdgcn_s_barrier();          // -> ALL waves' tile-0 loads landed

    // tile-0 phase-0 fragments
    short8 aA[4], bA[3], aB[4], bB[3];
#pragma unroll
    for (int mf = 0; mf < 4; ++mf) aA[mf] = *(const short8*)(lds + aoff + mf * 512);
#pragma unroll
    for (int nf = 0; nf < 3; ++nf) bA[nf] = *(const short8*)(lds + boff + nf * 512);

    // 64 K-tiles: t=0..60 steady (stage, vmcnt(6)); 61/62/63 drain 4/0/none.
    for (int i = 0; i < 15; ++i) {
        qkv_kstep<0, true, 6, true>(lds, acc, aA, bA, aB, bB, p0, p1, p2, p3, d0, d1, d2, d3, aoff, boff);
        qkv_kstep<1, true, 6, true>(lds, acc, aB, bB, aA, bA, p0, p1, p2, p3, d0, d1, d2, d3, aoff, boff);
        qkv_kstep<2, true, 6, true>(lds, acc, aA, bA, aB, bB, p0, p1, p2, p3, d0, d1, d2, d3, aoff, boff);
        qkv_kstep<3, true, 6, true>(lds, acc, aB, bB, aA, bA, p0, p1, p2, p3, d0, d1, d2, d3, aoff, boff);
    }
    qkv_kstep<0, true,  6, true >(lds, acc, aA, bA, aB, bB, p0, p1, p2, p3, d0, d1, d2, d3, aoff, boff); // t=60
    qkv_kstep<1, false, 4, true >(lds, acc, aB, bB, aA, bA, p0, p1, p2, p3, d0, d1, d2, d3, aoff, boff); // t=61
    qkv_kstep<2, false, 0, true >(lds, acc, aA, bA, aB, bB, p0, p1, p2, p3, d0, d1, d2, d3, aoff, boff); // t=62
    qkv_kstep<3, false, -1, false>(lds, acc, aB, bB, aA, bA, p0, p1, p2, p3, d0, d1, d2, d3, aoff, boff); // t=63

    // epilogue: C frag (mf,nf): row = q*4+reg, col = r. One head per block.
    const int head = nb;
    const int mbase = mb * 128 + wm * 64;
#pragma unroll
    for (int nf = 0; nf < 6; ++nf) {
        const int cb = wn * 96 + nf * 16;        // 0..368, multiple of 16
        const int sel = cb >> 7;                 // 0=Q 1=K 2=V (wave-uniform)
        const int e = (cb & 127) + r;
#pragma unroll
        for (int mf = 0; mf < 4; ++mf) {
            const int row0 = mbase + mf * 16 + q * 4;
            const f32x4 v = acc[mf][nf];
            if (sel == 2) {
                ushort4 o;
                o.x = f32_to_bf16(v[0]);
                o.y = f32_to_bf16(v[1]);
                o.z = f32_to_bf16(v[2]);
                o.w = f32_to_bf16(v[3]);
                *(ushort4*)&Vt[((size_t)head * EHEAD + e) * SEQ + row0] = o;
            } else {
                unsigned short* dst = sel ? Kb : Q;
#pragma unroll
                for (int reg = 0; reg < 4; ++reg)
                    dst[((size_t)head * SEQ + row0 + reg) * EHEAD + e] = f32_to_bf16(v[reg]);
            }
        }
    }
}

// ---------------- fused flash attention, 32x32 MFMA, VALU-stripped hot loop ----------------
__global__ __launch_bounds__(256, 2) void flash_attn(
        const unsigned short* __restrict__ Qg,
        const unsigned short* __restrict__ Kg,
        const unsigned short* __restrict__ Vtg,
        float* __restrict__ out) {
    extern __shared__ __attribute__((aligned(16))) unsigned short lds[];
    unsigned short* sQ  = lds;            // 8192 shorts = 16 KB   [64 m][128 k]
    unsigned short* sK0 = lds + 8192;     // 2 x 8192              [64 key][128 k]
    unsigned short* sV0 = lds + 24576;    // 2 x 8192              [128 e][64 key]

    const int tid = threadIdx.x;
    const int wave = tid >> 6, lane = tid & 63;
    const int l31 = lane & 31, q2 = lane >> 5;
    const int wm = wave >> 1, wn = wave & 1;
    const int b = blockIdx.x;
    const int h  = (b & 7) + (((b >> 3) >> 5) << 3);   // head -> XCD b%8 (K/V L2-resident)
    const int m0 = ((b >> 3) & 31) * 64;

    const unsigned short* Qh  = Qg  + ((size_t)h * SEQ + m0) * EHEAD;
    const unsigned short* Kh0 = Kg  + (size_t)h * SEQ * EHEAD;
    const unsigned short* Vh  = Vtg + (size_t)h * EHEAD * SEQ;

    const int qkRow = lane >> 4;
    const int qkPos = lane & 15;
    const int vRow  = lane >> 3;
    const int vPos  = lane & 7;

    const unsigned short* gK[4];
    const unsigned short* gV[4];
#pragma unroll
    for (int c = 0; c < 4; c++) {
        int u = wave * 4 + c;
        int row = u * 4 + qkRow;
        int ch = qkPos ^ (row & 7);
        gK[c] = Kh0 + (size_t)row * EHEAD + ch * 8;
        int rv = u * 8 + vRow;
        int cv = vPos ^ (rv & 7);
        gV[c] = Vh + (size_t)rv * SEQ + cv * 8;
        async_load16(Qh + (size_t)row * EHEAD + ch * 8, sQ + u * 512);
        async_load16(gK[c], sK0 + u * 512);
        async_load16(gV[c], sV0 + u * 512);
        gK[c] += 64 * EHEAD;
        gV[c] += 64;
    }
    __syncthreads();

    short8 bq[8];
    {
        const int row = wm * 32 + l31;
#pragma unroll
        for (int kc = 0; kc < 8; kc++) {
            int p = (kc * 2 + q2) ^ (row & 7);
            bq[kc] = *(const short8*)&sQ[row * 128 + p * 8];
        }
    }

    const unsigned short* kp[8];
    const unsigned short* vp[8];
    const int rowA = wn * 32 + l31;
#pragma unroll
    for (int kc = 0; kc < 8; kc++)
        kp[kc] = sK0 + rowA * 128 + (((kc * 2 + q2) ^ (rowA & 7)) * 8);
#pragma unroll
    for (int et = 0; et < 4; et++)
#pragma unroll
        for (int kc2 = 0; kc2 < 2; kc2++) {
            int rowV = et * 32 + l31;
            int cch = wn * 4 + kc2 * 2 + q2;
            vp[et * 2 + kc2] = sV0 + rowV * 64 + ((cch ^ (rowV & 7)) * 8);
        }

    const float c1 = 0.12752405856f;   // (1/sqrt(128)) * log2(e)
    f32x16 acc_o[4] = {};
    float l_acc = 0.f;

    auto body = [&](const int cur, const int nxt, bool pref) {
        if (pref) {
#pragma unroll
            for (int c = 0; c < 4; c++) {
                async_load16(gK[c], sK0 + nxt + (wave * 4 + c) * 512);
                gK[c] += 64 * EHEAD;
            }
#pragma unroll
            for (int c = 0; c < 4; c++) {
                async_load16(gV[c], sV0 + nxt + (wave * 4 + c) * 512);
                gV[c] += 64;
            }
        }

        f32x16 st = {};
#pragma unroll
        for (int kc = 0; kc < 8; kc++) {
            short8 ak = *(const short8*)(kp[kc] + cur);
            st = __builtin_amdgcn_mfma_f32_32x32x16_bf16(ak, bq[kc], st, 0, 0, 0);
        }

        unsigned int pk[8];
#pragma unroll
        for (int t = 0; t < 8; t++) {
            float p0 = __builtin_amdgcn_exp2f(st[2 * t] * c1);
            float p1 = __builtin_amdgcn_exp2f(st[2 * t + 1] * c1);
            l_acc += p0 + p1;
            unsigned int u0 = __float_as_uint(p0) + 0x8000u;
            unsigned int u1 = __float_as_uint(p1) + 0x8000u;
            pk[t] = __builtin_amdgcn_perm(u1, u0, 0x07060302u);
        }

        short8 fr[2];
#pragma unroll
        for (int kc2 = 0; kc2 < 2; kc2++) {
            unsigned int a0 = pk[kc2 * 4 + 0], a1 = pk[kc2 * 4 + 1];
            unsigned int a2 = pk[kc2 * 4 + 2], a3 = pk[kc2 * 4 + 3];
            unsigned int s0 = (unsigned int)__shfl_xor((int)a0, 32);
            unsigned int s1 = (unsigned int)__shfl_xor((int)a1, 32);
            unsigned int s2 = (unsigned int)__shfl_xor((int)a2, 32);
            unsigned int s3 = (unsigned int)__shfl_xor((int)a3, 32);
            uint4v t;
            t.x = q2 ? s2 : a0;
            t.y = q2 ? s3 : a1;
            t.z = q2 ? a2 : s0;
            t.w = q2 ? a3 : s1;
            fr[kc2] = __builtin_bit_cast(short8, t);
        }

#pragma unroll
        for (int et = 0; et < 4; et++)
#pragma unroll
            for (int kc2 = 0; kc2 < 2; kc2++) {
                short8 bv = *(const short8*)(vp[et * 2 + kc2] + cur);
                acc_o[et] = __builtin_amdgcn_mfma_f32_32x32x16_bf16(fr[kc2], bv, acc_o[et], 0, 0, 0);
            }
        __syncthreads();
    };

    for (int ip = 0; ip < SEQ / 128; ip++) {
        body(0, 8192, true);
        body(8192, 0, ip != SEQ / 128 - 1);
    }

    l_acc += __shfl_xor(l_acc, 32);

    float* fl = (float*)lds;
#pragma unroll
    for (int et = 0; et < 4; et++) {
        if ((et >> 1) != wn) {
#pragma unroll
            for (int rg = 0; rg < 4; rg++) {
                f32x4 v;
                v[0] = acc_o[et][rg * 4 + 0];
                v[1] = acc_o[et][rg * 4 + 1];
                v[2] = acc_o[et][rg * 4 + 2];
                v[3] = acc_o[et][rg * 4 + 3];
                *(f32x4*)&fl[(size_t)(((wm * 4 + et) * 4 + rg) * 256) + lane * 4] = v;
            }
        }
    }
    fl[8192 + (wm * 2 + wn) * 32 + l31] = l_acc;
    __syncthreads();

    float invq[4][4];
#pragma unroll
    for (int rg = 0; rg < 4; rg++)
#pragma unroll
        for (int i = 0; i < 4; i++) {
            int qy = i + 4 * q2 + 8 * rg;
            float lt = fl[8192 + (wm * 2 + 0) * 32 + qy] + fl[8192 + (wm * 2 + 1) * 32 + qy];
            invq[rg][i] = 1.0f / lt;
        }

#pragma unroll
    for (int et = 0; et < 4; et++) {
        if ((et >> 1) == wn) {
#pragma unroll
            for (int rg = 0; rg < 4; rg++) {
                f32x4 v = *(const f32x4*)&fl[(size_t)(((wm * 4 + et) * 4 + rg) * 256) + lane * 4];
#pragma unroll
                for (int i = 0; i < 4; i++) {
                    int mrow = i + 4 * q2 + 8 * rg;
                    out[(size_t)(m0 + wm * 32 + mrow) * DMODEL + h * EHEAD + et * 32 + l31] =
                        (acc_o[et][rg * 4 + i] + v[i]) * invq[rg][i];
                }
            }
        }
    }
}

extern "C" void kernel_launch(void* const* d_in, const int* in_sizes, int n_in,
                              void* d_out, int out_size, void* d_ws, size_t ws_size,
                              hipStream_t stream) {
    const float* x = (const float*)d_in[0];      // [S][D]
    const float* w = (const float*)d_in[1];      // [H][D][3E]
    float* out = (float*)d_out;                  // [S][H*E]

    char* ws = (char*)d_ws;
    unsigned short* xb = (unsigned short*)(ws);                        //  8 MB
    unsigned short* wT = (unsigned short*)(ws + 8388608);              // 24 MB
    unsigned short* Q  = (unsigned short*)(ws + 33554432);             //  8 MB
    unsigned short* Kb = (unsigned short*)(ws + 41943040);             //  8 MB
    unsigned short* Vt = (unsigned short*)(ws + 50331648);             //  8 MB

    static bool attr_set = false;
    if (!attr_set) {
        hipFuncSetAttribute((const void*)flash_attn,
                            hipFuncAttributeMaxDynamicSharedMemorySize, 81920);
        hipFuncSetAttribute((const void*)qkv_gemm384,
                            hipFuncAttributeMaxDynamicSharedMemorySize, 131072);
        attr_set = true;
    }

    cast_x_kernel<<<SEQ * DMODEL / (256 * 4), 256, 0, stream>>>(x, xb);
    transpose_w_kernel<<<dim3(DMODEL / 64, NE3 / 64, NHEAD), 256, 0, stream>>>(w, wT);
    qkv_gemm384<<<dim3(SEQ / 128, NHEAD), 512, 131072, stream>>>(xb, wT, Q, Kb, Vt);
    flash_attn<<<512, 256, 81920, stream>>>(Q, Kb, Vt, out);
}